// Round 8
// baseline (1165.785 us; speedup 1.0000x reference)
//
#include <hip/hip_runtime.h>
#include <math.h>

// ---------------------------------------------------------------------------
// AttentionalSpikingSSMLayer  (B=8, T=16, S=256, D=512, DS=64, H=4, dh=16)
// All compute fp32 (no fp32 MFMA on CDNA4; Heaviside spikes need fp32 margin).
// R2: kv_gemm vectorized LDS; combine dense b128 dots. (1002 us)
// R3: NSPLIT 16 REGRESSED (1143); R4: coop mega REGRESSED (2767, L2 flush);
// R5: packed fp32 REGRESSED (1195, LDS-bound not VALU).
// R6: NSPLIT=32 + exp2f + sparse ballot dots. (974 us)
// R7: kv conflict fix (null) + sparse hmask out-gather from C_t. (910 us)
// R8: out folded into combine REGRESSED (932): lost out||attp overlap.
// R9: kv column-split NULL (occupancy 17->29%, dur flat: DS-issue-bound).
//     kv frozen at R7 form; reverted.
// R10: attp in-block key-split: 2 groups x 32 keys, 4 queries/thread, LDS
//     flash-merge. DS broadcast reads were the binding pipe (512 b128/thread,
//     ~20us/dispatch); now 256+merge ~= 1.7x fewer. Same split-combine math
//     one tree level deeper (R3/R6-class reorder). pacc/NSPLIT unchanged.
// ---------------------------------------------------------------------------

#define NTOK   2048          // B*S
#define TSTEPS 16
#define NSPLIT 32            // key splits for flash partials (64 keys each)

#define MEMDECAY ((float)0.6065306597126334)
#define SCALE    0.25f       // 1/sqrt(dh)
#define LOG2E    1.4426950408889634f

// workspace layout (float offsets)
#define OFF_KV   ((size_t)0)                      // 16*2048*128
#define OFF_PACC ((size_t)4194304)                // 4*32*2048*16
#define OFF_OV   ((size_t)8388608)                // 2048*512
#define OFF_SV   ((size_t)9568256)
#define OFF_Q    ((size_t)9699328)
#define OFF_PM   ((size_t)9830400)                // 4*32*2048
#define OFF_PL   ((size_t)10092544)               // 4*32*2048
#define OFF_CT   ((size_t)10354688)               // 64*512 (C transposed)
#define OFF_CNT  ((size_t)10387456)               // 32 ints: [0..15]=s, [16..31]=o
#define OFF_WT   ((size_t)10387488)               // 512*128 (Wkv transposed)
#define OFF_HM   ((size_t)10453024)               // 2048 uint64 spike masks

#define ATTP_SMEM 12288      // floats: kl 1024 | vl 1024 | ab 512*20

// ---------------------------------------------------------------------------
// init: zero ov+sv, q <- bq, C_t transpose, Wkv_t transpose, zero counters,
// zero spike masks.
// ---------------------------------------------------------------------------
__global__ __launch_bounds__(256) void init_kernel(const float* __restrict__ bq,
                                                   const float* __restrict__ C,
                                                   const float* __restrict__ Wkv,
                                                   float* __restrict__ ws) {
  int i = blockIdx.x * 256 + threadIdx.x;
  if (i < 327680) {                       // zero ov + (h) + sv (float4)
    float4 z = {0.f, 0.f, 0.f, 0.f};
    ((float4*)(ws + OFF_OV))[i] = z;
    return;
  }
  i -= 327680;
  if (i < 131072) { ws[OFF_Q + i] = bq[i & 63]; return; }
  i -= 131072;
  if (i < 32768) {                        // C_t[k][c] = C[c][k]
    int k = i >> 9, c = i & 511;
    ws[OFF_CT + i] = C[c * 64 + k];
    return;
  }
  i -= 32768;
  if (i < 65536) {                        // Wkv_t[k][o] = Wkv[o][k]
    int k = i >> 7, o = i & 127;
    ws[OFF_WT + i] = Wkv[o * 512 + k];
    return;
  }
  i -= 65536;
  if (i < 32) { ((int*)(ws + OFF_CNT))[i] = 0; return; }
  i -= 32;
  if (i < 1024) {                         // zero hmask (1024 float4)
    float4 z = {0.f, 0.f, 0.f, 0.f};
    ((float4*)(ws + OFF_HM))[i] = z;
  }
}

// ---------------------------------------------------------------------------
// KV projection (R7 proven form, frozen): 512 blocks, 64 rows x 128 cols.
// ---------------------------------------------------------------------------
__global__ __launch_bounds__(256) void kv_gemm_kernel(const float* __restrict__ x,
                                                      const float* __restrict__ wkt,
                                                      const float* __restrict__ bkv,
                                                      float* __restrict__ ws) {
  __shared__ float xs[64 * 68];        // rows x k, stride 68
  __shared__ float wt[64 * 136];       // k x cols, stride 136
  const int tid = threadIdx.x;
  const int mbase = blockIdx.x * 64;
  const int rg = tid >> 4;             // rows rg*4 .. rg*4+3
  const int cg = tid & 15;             // cols cg*4..+3 and 64+cg*4..+3

  float acc[4][8];
#pragma unroll
  for (int i = 0; i < 4; ++i)
#pragma unroll
    for (int j = 0; j < 8; ++j) acc[i][j] = 0.f;

  for (int kt = 0; kt < 8; ++kt) {
    const int kb = kt * 64;
#pragma unroll
    for (int p = 0; p < 4; ++p) {
      int e = tid + p * 256;
      int r = e >> 4, kq = e & 15;
      int row = mbase + r;
      int t_ = row >> 11, n = row & 2047;
      int b = n >> 8, s = n & 255;
      float4 v = *(const float4*)(x + (size_t)((b * 16 + t_) * 256 + s) * 512 + kb + kq * 4);
      *(float4*)(xs + r * 68 + kq * 4) = v;
    }
#pragma unroll
    for (int p = 0; p < 8; ++p) {
      int e = tid + p * 256;
      int k = e >> 5, cq = e & 31;
      float4 v = *(const float4*)(wkt + (size_t)(kb + k) * 128 + cq * 4);
      *(float4*)(wt + k * 136 + cq * 4) = v;
    }
    __syncthreads();
#pragma unroll 2
    for (int kq = 0; kq < 16; ++kq) {
      float4 a0 = *(const float4*)(xs + (rg * 4 + 0) * 68 + kq * 4);
      float4 a1 = *(const float4*)(xs + (rg * 4 + 1) * 68 + kq * 4);
      float4 a2 = *(const float4*)(xs + (rg * 4 + 2) * 68 + kq * 4);
      float4 a3 = *(const float4*)(xs + (rg * 4 + 3) * 68 + kq * 4);
      const float* ap[4] = {(const float*)&a0, (const float*)&a1,
                            (const float*)&a2, (const float*)&a3};
#pragma unroll
      for (int kk = 0; kk < 4; ++kk) {
        const float* wp = wt + (kq * 4 + kk) * 136;
        float4 b0 = *(const float4*)(wp + cg * 4);
        float4 b1 = *(const float4*)(wp + 64 + cg * 4);
#pragma unroll
        for (int i = 0; i < 4; ++i) {
          float av = ap[i][kk];
          acc[i][0] += av * b0.x; acc[i][1] += av * b0.y;
          acc[i][2] += av * b0.z; acc[i][3] += av * b0.w;
          acc[i][4] += av * b1.x; acc[i][5] += av * b1.y;
          acc[i][6] += av * b1.z; acc[i][7] += av * b1.w;
        }
      }
    }
    __syncthreads();
  }
  float4 bb0 = *(const float4*)(bkv + cg * 4);
  float4 bb1 = *(const float4*)(bkv + 64 + cg * 4);
  float* kvout = ws + OFF_KV;
#pragma unroll
  for (int i = 0; i < 4; ++i) {
    float* op = kvout + (size_t)(mbase + rg * 4 + i) * 128;
    float4 v0; v0.x = acc[i][0] + bb0.x; v0.y = acc[i][1] + bb0.y;
    v0.z = acc[i][2] + bb0.z; v0.w = acc[i][3] + bb0.w;
    float4 v1; v1.x = acc[i][4] + bb1.x; v1.y = acc[i][5] + bb1.y;
    v1.z = acc[i][6] + bb1.z; v1.w = acc[i][7] + bb1.w;
    *(float4*)(op + cg * 4) = v0;
    *(float4*)(op + 64 + cg * 4) = v1;
  }
}

// ---------------------------------------------------------------------------
// attention partials (flash, key-split). blk: head(2b) | qtile(2b) | split(5b)
// 256 thr. In-block key split: grp = tid>>7 handles keys [grp*32, grp*32+32)
// for 4 queries/thread (qt*512 + lt + r*128). Group 1 posts its flash state
// to LDS (ab[q][20]: acc16|m|l); group 0 merges and writes final partials.
// ---------------------------------------------------------------------------
__device__ __forceinline__ void attp_body(int blk, int tid, int t,
                                          const float* __restrict__ kvbase,
                                          const float* __restrict__ qbuf,
                                          float* __restrict__ pm,
                                          float* __restrict__ pl,
                                          float* __restrict__ pacc,
                                          float* smem) {
  const int head = blk & 3;
  const int qt = (blk >> 2) & 3;
  const int sp = blk >> 4;                 // 0..31
  float* kl = smem;                        // [64][16]
  float* vl = smem + 1024;                 // [64][16]
  float* ab = smem + 2048;                 // [512][20]
  const float* kvt = kvbase + (size_t)t * NTOK * 128;
  {
    int key = tid >> 2, dq = tid & 3;
    const float* base = kvt + (size_t)(sp * 64 + key) * 128 + head * 16;
    ((float4*)kl)[key * 4 + dq] = ((const float4*)base)[dq];
    ((float4*)vl)[key * 4 + dq] = ((const float4*)(base + 64))[dq];
  }
  const int grp = tid >> 7;                // key half 0/1
  const int lt = tid & 127;
  float q[4][16];
#pragma unroll
  for (int r = 0; r < 4; ++r) {
    const float4* qp = (const float4*)(qbuf + (size_t)(qt * 512 + lt + r * 128) * 64 + head * 16);
#pragma unroll
    for (int x = 0; x < 4; ++x) {
      float4 a = qp[x];
      q[r][4 * x] = a.x; q[r][4 * x + 1] = a.y;
      q[r][4 * x + 2] = a.z; q[r][4 * x + 3] = a.w;
    }
  }
  __syncthreads();
  float m[4], l[4], acc[4][16];
#pragma unroll
  for (int r = 0; r < 4; ++r) {
    m[r] = -INFINITY; l[r] = 0.f;
#pragma unroll
    for (int d = 0; d < 16; ++d) acc[r][d] = 0.f;
  }
  const int kb = grp * 32;
#pragma unroll
  for (int ch = 0; ch < 4; ++ch) {         // 8-key chunks (VGPR-friendly)
    float sc[4][8];
#pragma unroll
    for (int j = 0; j < 8; ++j) {
      const float* kp = kl + (kb + ch * 8 + j) * 16;
      float s0 = 0.f, s1 = 0.f, s2 = 0.f, s3 = 0.f;
#pragma unroll
      for (int d = 0; d < 16; ++d) {
        float kvv = kp[d];
        s0 += q[0][d] * kvv; s1 += q[1][d] * kvv;
        s2 += q[2][d] * kvv; s3 += q[3][d] * kvv;
      }
      sc[0][j] = s0 * SCALE; sc[1][j] = s1 * SCALE;
      sc[2][j] = s2 * SCALE; sc[3][j] = s3 * SCALE;
    }
#pragma unroll
    for (int r = 0; r < 4; ++r) {
      float mbv = sc[r][0];
#pragma unroll
      for (int j = 1; j < 8; ++j) mbv = fmaxf(mbv, sc[r][j]);
      float mn = fmaxf(m[r], mbv);
      float rr = exp2f((m[r] - mn) * LOG2E);
      l[r] *= rr;
#pragma unroll
      for (int d = 0; d < 16; ++d) acc[r][d] *= rr;
#pragma unroll
      for (int j = 0; j < 8; ++j) {
        float w = exp2f((sc[r][j] - mn) * LOG2E);
        l[r] += w; sc[r][j] = w;
      }
      m[r] = mn;
    }
#pragma unroll
    for (int j = 0; j < 8; ++j) {
      const float* vp = vl + (kb + ch * 8 + j) * 16;
#pragma unroll
      for (int d = 0; d < 16; ++d) {
        float vv = vp[d];
        acc[0][d] += sc[0][j] * vv; acc[1][d] += sc[1][j] * vv;
        acc[2][d] += sc[2][j] * vv; acc[3][d] += sc[3][j] * vv;
      }
    }
  }
  if (grp == 1) {
#pragma unroll
    for (int r = 0; r < 4; ++r) {
      int qi = lt + r * 128;
      float* row = ab + qi * 20;
#pragma unroll
      for (int x = 0; x < 4; ++x) {
        float4 v; v.x = acc[r][4 * x]; v.y = acc[r][4 * x + 1];
        v.z = acc[r][4 * x + 2]; v.w = acc[r][4 * x + 3];
        *(float4*)(row + x * 4) = v;
      }
      row[16] = m[r]; row[17] = l[r];
    }
  }
  __syncthreads();
  if (grp == 0) {
    const int pbase = (head * NSPLIT + sp) * NTOK;
#pragma unroll
    for (int r = 0; r < 4; ++r) {
      int qi = lt + r * 128;
      const float* row = ab + qi * 20;
      float m1 = row[16], l1 = row[17];
      float mn = fmaxf(m[r], m1);
      float r0 = exp2f((m[r] - mn) * LOG2E);
      float r1 = exp2f((m1 - mn) * LOG2E);
      int i = qt * 512 + qi;
      pm[pbase + i] = mn;
      pl[pbase + i] = l[r] * r0 + l1 * r1;
      float4* pa = (float4*)(pacc + (size_t)(pbase + i) * 16);
#pragma unroll
      for (int x = 0; x < 4; ++x) {
        float4 a1 = *(const float4*)(row + x * 4);
        float4 v;
        v.x = acc[r][4 * x] * r0 + a1.x * r1;
        v.y = acc[r][4 * x + 1] * r0 + a1.y * r1;
        v.z = acc[r][4 * x + 2] * r0 + a1.z * r1;
        v.w = acc[r][4 * x + 3] * r0 + a1.w * r1;
        pa[x] = v;
      }
    }
  }
}

__global__ __launch_bounds__(256) void attp_kernel(int t, float* __restrict__ ws) {
  __shared__ float smem[ATTP_SMEM];
  attp_body(blockIdx.x, threadIdx.x, t, ws + OFF_KV, ws + OFF_Q,
            ws + OFF_PM, ws + OFF_PL, ws + OFF_PACC, smem);
}

// ---------------------------------------------------------------------------
// combine partials -> att ; su = h@A.T + att@Wo.T + bo ; LIF-S; q(t+1).
// One wave per token. Spike state lives as 64-bit masks (OFF_HM). Sparse
// sums ascending-k == dense chain. (R7 proven form)
// ---------------------------------------------------------------------------
__global__ __launch_bounds__(256) void combine_lifs_kernel(
    int t, const float* __restrict__ A, const float* __restrict__ Wq,
    const float* __restrict__ bq, const float* __restrict__ Wo,
    const float* __restrict__ bo, const float* __restrict__ thr_s0,
    float* __restrict__ ws) {
  __shared__ float As[64 * 68], Wqs[64 * 68], Wos[64 * 68];  // row-major, c x k
  __shared__ float att_s[4][64];
  __shared__ int scnt;
  const int tid = threadIdx.x;
#pragma unroll
  for (int p = 0; p < 4; ++p) {
    int e = tid + p * 256;
    int c = e >> 4, kq = e & 15;
    *(float4*)(As + c * 68 + kq * 4)  = *(const float4*)(A + c * 64 + kq * 4);
    *(float4*)(Wqs + c * 68 + kq * 4) = *(const float4*)(Wq + c * 64 + kq * 4);
    *(float4*)(Wos + c * 68 + kq * 4) = *(const float4*)(Wo + c * 64 + kq * 4);
  }
  if (tid == 0) scnt = 0;

  const float* pm = ws + OFF_PM;
  const float* pl = ws + OFF_PL;
  const float* pacc = ws + OFF_PACC;
  float* sv = ws + OFF_SV;
  float* qb = ws + OFF_Q;
  int* cnt = (int*)(ws + OFF_CNT);
  unsigned long long* hmask = (unsigned long long*)(ws + OFF_HM);

  const int lane = tid & 63, w = tid >> 6;
  const int n = blockIdx.x * 4 + w;
  const int head = lane >> 4, d = lane & 15;
  const int pb = head * NSPLIT * NTOK + n;

  float mstar = -INFINITY;
  for (int s = 0; s < NSPLIT; ++s) mstar = fmaxf(mstar, pm[pb + s * NTOK]);
  float lst = 0.f, av = 0.f;
  for (int s = 0; s < NSPLIT; ++s) {
    float e = exp2f((pm[pb + s * NTOK] - mstar) * LOG2E);
    lst += e * pl[pb + s * NTOK];
    av += e * pacc[(size_t)(pb + s * NTOK) * 16 + d];
  }
  att_s[w][lane] = av / lst;
  unsigned long long hm = hmask[n];        // previous spike mask, wave-uniform
  __syncthreads();

  // sparse st = sum_{k in hm} A[lane][k]  (ascending k; == dense fma chain)
  float st = 0.f;
  {
    unsigned long long m = hm;
    while (m) {
      int k = __builtin_ctzll(m);
      m &= m - 1;
      st += As[lane * 68 + k];
    }
  }
  // dense wo = sum_k att[k]*Wo[lane][k]
  const float* Wor = Wos + lane * 68;
  float wo = 0.f;
#pragma unroll
  for (int kq = 0; kq < 16; ++kq) {
    float4 wb = *(const float4*)(Wor + kq * 4);
    float4 ab = *(const float4*)(&att_s[w][kq * 4]);
    wo += ab.x * wb.x; wo += ab.y * wb.y; wo += ab.z * wb.z; wo += ab.w * wb.w;
  }
  float su = st + wo + bo[lane];

  float thr = thr_s0[0];
  const float inv = 1.0f / 131072.0f;      // 2048*64 (power of 2 -> exact)
  for (int i = 0; i < t; ++i) {
    float mean = (float)cnt[i] * inv;
    thr = fmaxf(thr + 0.1f * (mean - 0.02f), 0.5f);
  }
  float svo = sv[n * 64 + lane];
  float vpot = svo * MEMDECAY + su;
  float spk = (vpot >= thr) ? 1.f : 0.f;
  sv[n * 64 + lane] = vpot * (1.f - spk);
  unsigned long long sm = __ballot(spk > 0.5f);  // wave-uniform

  // sparse q = sum_{k in sm} Wq[lane][k] + bq[lane]
  float qv = 0.f;
  {
    unsigned long long m = sm;
    while (m) {
      int k = __builtin_ctzll(m);
      m &= m - 1;
      qv += Wqs[lane * 68 + k];
    }
  }
  qb[n * 64 + lane] = qv + bq[lane];

  if (lane == 0) {
    hmask[n] = sm;
    atomicAdd(&scnt, __popcll(sm));
  }
  __syncthreads();
  if (tid == 0) atomicAdd(&cnt[t], scnt);
}

// ---------------------------------------------------------------------------
// LIF-O sparse: out_pot[n][c] = sum_{k in hmask[n]} C_t[k][c]; fused LIF
// epilogue. C_t L2-resident, no staging. Fused with attp(t+1) in [256,768).
// ---------------------------------------------------------------------------
__global__ __launch_bounds__(256) void fused_out_attp_kernel(
    int t, const float* __restrict__ thr_o0, float* __restrict__ out,
    float* __restrict__ ws) {
  __shared__ float smem[ATTP_SMEM];
  __shared__ int scnt;
  const int blk = blockIdx.x;
  if (blk >= 256) {
    attp_body(blk - 256, threadIdx.x, t + 1, ws + OFF_KV, ws + OFF_Q,
              ws + OFF_PM, ws + OFF_PL, ws + OFF_PACC, smem);
    return;
  }
  const int tid = threadIdx.x;
  const int nt = blk >> 3;                  // token tile 0..31
  const int ct = blk & 7;                   // channel tile 0..7
  const float* Ct = ws + OFF_CT;
  float* ov = ws + OFF_OV;
  int* cnt = (int*)(ws + OFF_CNT);
  const unsigned long long* hmask = (const unsigned long long*)(ws + OFF_HM);

  if (tid == 0) scnt = 0;
  __syncthreads();

  const int tr = tid >> 4, tc = tid & 15;   // rows tr+i*16, cols tc*4+j
  float thr = thr_o0[0];
  const float inv = 1.0f / 1048576.0f;      // 2048*512
  for (int i = 0; i < t; ++i) {
    float mean = (float)cnt[16 + i] * inv;
    thr = fmaxf(thr + 0.1f * (mean - 0.02f), 0.5f);
  }

  int mycount = 0;
#pragma unroll
  for (int i = 0; i < 4; ++i) {
    int n = nt * 64 + tr + i * 16;
    size_t coff = (size_t)ct * 64 + tc * 4;
    // sparse gather: ascending-k adds == dense fma chain (h in {0,1})
    float a0 = 0.f, a1 = 0.f, a2 = 0.f, a3 = 0.f;
    unsigned long long m = hmask[n];
    while (m) {
      int k = __builtin_ctzll(m);
      m &= m - 1;
      float4 c = *(const float4*)(Ct + (size_t)k * 512 + coff);
      a0 += c.x; a1 += c.y; a2 += c.z; a3 += c.w;
    }
    int b = n >> 8, s = n & 255;
    float* ovp = ov + (size_t)n * 512 + coff;
    float* outp = out + ((size_t)(b * 16 + t) * 256 + s) * 512 + coff;
    float4 o = *(float4*)ovp;
    float v0 = o.x * MEMDECAY + a0;
    float v1 = o.y * MEMDECAY + a1;
    float v2 = o.z * MEMDECAY + a2;
    float v3 = o.w * MEMDECAY + a3;
    float s0 = (v0 >= thr) ? 1.f : 0.f;
    float s1 = (v1 >= thr) ? 1.f : 0.f;
    float s2 = (v2 >= thr) ? 1.f : 0.f;
    float s3 = (v3 >= thr) ? 1.f : 0.f;
    float4 sp; sp.x = s0; sp.y = s1; sp.z = s2; sp.w = s3;
    *(float4*)outp = sp;
    float4 nv; nv.x = v0 * (1.f - s0); nv.y = v1 * (1.f - s1);
    nv.z = v2 * (1.f - s2); nv.w = v3 * (1.f - s3);
    *(float4*)ovp = nv;
    mycount += (int)(s0 + s1 + s2 + s3);
  }
  atomicAdd(&scnt, mycount);
  __syncthreads();
  if (tid == 0) atomicAdd(&cnt[16 + t], scnt);
}

// ---------------------------------------------------------------------------
extern "C" void kernel_launch(void* const* d_in, const int* in_sizes, int n_in,
                              void* d_out, int out_size, void* d_ws, size_t ws_size,
                              hipStream_t stream) {
  const float* x    = (const float*)d_in[0];
  const float* A    = (const float*)d_in[1];
  const float* C    = (const float*)d_in[2];
  const float* Wq   = (const float*)d_in[3];
  const float* bq   = (const float*)d_in[4];
  const float* Wkv  = (const float*)d_in[5];
  const float* bkv  = (const float*)d_in[6];
  const float* Wo   = (const float*)d_in[7];
  const float* bo   = (const float*)d_in[8];
  const float* th_s = (const float*)d_in[9];
  const float* th_o = (const float*)d_in[10];
  float* out = (float*)d_out;
  float* ws = (float*)d_ws;

  init_kernel<<<dim3(2181), dim3(256), 0, stream>>>(bq, C, Wkv, ws);
  kv_gemm_kernel<<<dim3(512), dim3(256), 0, stream>>>(x, ws + OFF_WT, bkv, ws);
  attp_kernel<<<dim3(512), dim3(256), 0, stream>>>(0, ws);
  for (int t = 0; t < TSTEPS; ++t) {
    combine_lifs_kernel<<<dim3(512), dim3(256), 0, stream>>>(t, A, Wq, bq, Wo, bo, th_s, ws);
    int g = (t < TSTEPS - 1) ? 768 : 256;
    fused_out_attp_kernel<<<dim3(g), dim3(256), 0, stream>>>(t, th_o, out, ws);
  }
}

// Round 9
// 911.609 us; speedup vs baseline: 1.2788x; 1.2788x over previous
//
#include <hip/hip_runtime.h>
#include <math.h>

// ---------------------------------------------------------------------------
// AttentionalSpikingSSMLayer  (B=8, T=16, S=256, D=512, DS=64, H=4, dh=16)
// All compute fp32 (no fp32 MFMA on CDNA4; Heaviside spikes need fp32 margin).
// R2: kv_gemm vectorized LDS; combine dense b128 dots. (1002 us)
// R3: NSPLIT 16 REGRESSED (1143); R4: coop mega REGRESSED (2767, L2 flush);
// R5: packed fp32 REGRESSED (1195, LDS-bound not VALU).
// R6: NSPLIT=32 + exp2f + sparse ballot dots. (974 us)
// R7: kv conflict fix (null) + sparse hmask out-gather from C_t. (910 us)
// R8: out folded into combine REGRESSED (932): lost out||attp overlap.
// R9: kv column-split NULL (occupancy 17->29%, dur flat: DS-issue-bound).
// R10: attp in-block key-split REGRESSED (1165): 48KB merge LDS halved
//      occupancy + VGPR spill. attp reverted to R7 form; DS-broadcast
//      theory retired (uniform-addr LDS reads are 1-issue broadcasts).
// R11: R7 baseline + combine staging slim: stage ONLY Wos (dense use);
//      sparse A/Wq terms (~1.3/lane) read direct from L2. LDS 52.6->18KB,
//      -16MB/step tile traffic. Attribution test for R8's bundle.
//      attp: q global-loads issued before K/V LDS stores (latency hide).
// ---------------------------------------------------------------------------

#define NTOK   2048          // B*S
#define TSTEPS 16
#define NSPLIT 32            // key splits for flash partials (64 keys each)

#define MEMDECAY ((float)0.6065306597126334)
#define SCALE    0.25f       // 1/sqrt(dh)
#define LOG2E    1.4426950408889634f

// workspace layout (float offsets)
#define OFF_KV   ((size_t)0)                      // 16*2048*128
#define OFF_PACC ((size_t)4194304)                // 4*32*2048*16
#define OFF_OV   ((size_t)8388608)                // 2048*512
#define OFF_SV   ((size_t)9568256)
#define OFF_Q    ((size_t)9699328)
#define OFF_PM   ((size_t)9830400)                // 4*32*2048
#define OFF_PL   ((size_t)10092544)               // 4*32*2048
#define OFF_CT   ((size_t)10354688)               // 64*512 (C transposed)
#define OFF_CNT  ((size_t)10387456)               // 32 ints: [0..15]=s, [16..31]=o
#define OFF_WT   ((size_t)10387488)               // 512*128 (Wkv transposed)
#define OFF_HM   ((size_t)10453024)               // 2048 uint64 spike masks

// ---------------------------------------------------------------------------
// init: zero ov+sv, q <- bq, C_t transpose, Wkv_t transpose, zero counters,
// zero spike masks.
// ---------------------------------------------------------------------------
__global__ __launch_bounds__(256) void init_kernel(const float* __restrict__ bq,
                                                   const float* __restrict__ C,
                                                   const float* __restrict__ Wkv,
                                                   float* __restrict__ ws) {
  int i = blockIdx.x * 256 + threadIdx.x;
  if (i < 327680) {                       // zero ov + (h) + sv (float4)
    float4 z = {0.f, 0.f, 0.f, 0.f};
    ((float4*)(ws + OFF_OV))[i] = z;
    return;
  }
  i -= 327680;
  if (i < 131072) { ws[OFF_Q + i] = bq[i & 63]; return; }
  i -= 131072;
  if (i < 32768) {                        // C_t[k][c] = C[c][k]
    int k = i >> 9, c = i & 511;
    ws[OFF_CT + i] = C[c * 64 + k];
    return;
  }
  i -= 32768;
  if (i < 65536) {                        // Wkv_t[k][o] = Wkv[o][k]
    int k = i >> 7, o = i & 127;
    ws[OFF_WT + i] = Wkv[o * 512 + k];
    return;
  }
  i -= 65536;
  if (i < 32) { ((int*)(ws + OFF_CNT))[i] = 0; return; }
  i -= 32;
  if (i < 1024) {                         // zero hmask (1024 float4)
    float4 z = {0.f, 0.f, 0.f, 0.f};
    ((float4*)(ws + OFF_HM))[i] = z;
  }
}

// ---------------------------------------------------------------------------
// KV projection (R7 proven form, frozen): 512 blocks, 64 rows x 128 cols.
// ---------------------------------------------------------------------------
__global__ __launch_bounds__(256) void kv_gemm_kernel(const float* __restrict__ x,
                                                      const float* __restrict__ wkt,
                                                      const float* __restrict__ bkv,
                                                      float* __restrict__ ws) {
  __shared__ float xs[64 * 68];        // rows x k, stride 68
  __shared__ float wt[64 * 136];       // k x cols, stride 136
  const int tid = threadIdx.x;
  const int mbase = blockIdx.x * 64;
  const int rg = tid >> 4;             // rows rg*4 .. rg*4+3
  const int cg = tid & 15;             // cols cg*4..+3 and 64+cg*4..+3

  float acc[4][8];
#pragma unroll
  for (int i = 0; i < 4; ++i)
#pragma unroll
    for (int j = 0; j < 8; ++j) acc[i][j] = 0.f;

  for (int kt = 0; kt < 8; ++kt) {
    const int kb = kt * 64;
#pragma unroll
    for (int p = 0; p < 4; ++p) {
      int e = tid + p * 256;
      int r = e >> 4, kq = e & 15;
      int row = mbase + r;
      int t_ = row >> 11, n = row & 2047;
      int b = n >> 8, s = n & 255;
      float4 v = *(const float4*)(x + (size_t)((b * 16 + t_) * 256 + s) * 512 + kb + kq * 4);
      *(float4*)(xs + r * 68 + kq * 4) = v;
    }
#pragma unroll
    for (int p = 0; p < 8; ++p) {
      int e = tid + p * 256;
      int k = e >> 5, cq = e & 31;
      float4 v = *(const float4*)(wkt + (size_t)(kb + k) * 128 + cq * 4);
      *(float4*)(wt + k * 136 + cq * 4) = v;
    }
    __syncthreads();
#pragma unroll 2
    for (int kq = 0; kq < 16; ++kq) {
      float4 a0 = *(const float4*)(xs + (rg * 4 + 0) * 68 + kq * 4);
      float4 a1 = *(const float4*)(xs + (rg * 4 + 1) * 68 + kq * 4);
      float4 a2 = *(const float4*)(xs + (rg * 4 + 2) * 68 + kq * 4);
      float4 a3 = *(const float4*)(xs + (rg * 4 + 3) * 68 + kq * 4);
      const float* ap[4] = {(const float*)&a0, (const float*)&a1,
                            (const float*)&a2, (const float*)&a3};
#pragma unroll
      for (int kk = 0; kk < 4; ++kk) {
        const float* wp = wt + (kq * 4 + kk) * 136;
        float4 b0 = *(const float4*)(wp + cg * 4);
        float4 b1 = *(const float4*)(wp + 64 + cg * 4);
#pragma unroll
        for (int i = 0; i < 4; ++i) {
          float av = ap[i][kk];
          acc[i][0] += av * b0.x; acc[i][1] += av * b0.y;
          acc[i][2] += av * b0.z; acc[i][3] += av * b0.w;
          acc[i][4] += av * b1.x; acc[i][5] += av * b1.y;
          acc[i][6] += av * b1.z; acc[i][7] += av * b1.w;
        }
      }
    }
    __syncthreads();
  }
  float4 bb0 = *(const float4*)(bkv + cg * 4);
  float4 bb1 = *(const float4*)(bkv + 64 + cg * 4);
  float* kvout = ws + OFF_KV;
#pragma unroll
  for (int i = 0; i < 4; ++i) {
    float* op = kvout + (size_t)(mbase + rg * 4 + i) * 128;
    float4 v0; v0.x = acc[i][0] + bb0.x; v0.y = acc[i][1] + bb0.y;
    v0.z = acc[i][2] + bb0.z; v0.w = acc[i][3] + bb0.w;
    float4 v1; v1.x = acc[i][4] + bb1.x; v1.y = acc[i][5] + bb1.y;
    v1.z = acc[i][6] + bb1.z; v1.w = acc[i][7] + bb1.w;
    *(float4*)(op + cg * 4) = v0;
    *(float4*)(op + 64 + cg * 4) = v1;
  }
}

// ---------------------------------------------------------------------------
// attention partials (flash, key-split). blk: head(2b) | qtile(2b) | split(5b)
// 256 thr, 2 queries/thread, 64 keys/block. exp via exp2f on reduced args.
// q global-loads issued before K/V LDS stores (latency hides under staging).
// ---------------------------------------------------------------------------
__device__ __forceinline__ void attp_body(int blk, int tid, int t,
                                          const float* __restrict__ kvbase,
                                          const float* __restrict__ qbuf,
                                          float* __restrict__ pm,
                                          float* __restrict__ pl,
                                          float* __restrict__ pacc,
                                          float* smem) {
  const int head = blk & 3;
  const int qt = (blk >> 2) & 3;
  const int sp = blk >> 4;                 // 0..31
  float* kl = smem;                        // [64][16]
  float* vl = smem + 1024;
  const float* kvt = kvbase + (size_t)t * NTOK * 128;
  const int i0 = qt * 512 + tid;
  const int i1 = i0 + 256;
  // issue q loads first (independent of staging)
  float4 qa[4], qb4[4];
  {
    const float4* qp0 = (const float4*)(qbuf + (size_t)i0 * 64 + head * 16);
    const float4* qp1 = (const float4*)(qbuf + (size_t)i1 * 64 + head * 16);
#pragma unroll
    for (int r = 0; r < 4; ++r) { qa[r] = qp0[r]; qb4[r] = qp1[r]; }
  }
  {
    int key = tid >> 2, dq = tid & 3;
    const float* base = kvt + (size_t)(sp * 64 + key) * 128 + head * 16;
    float4 kk = ((const float4*)base)[dq];
    float4 vv = ((const float4*)(base + 64))[dq];
    ((float4*)kl)[key * 4 + dq] = kk;
    ((float4*)vl)[key * 4 + dq] = vv;
  }
  float q0[16], q1[16];
#pragma unroll
  for (int r = 0; r < 4; ++r) {
    q0[4 * r] = qa[r].x; q0[4 * r + 1] = qa[r].y;
    q0[4 * r + 2] = qa[r].z; q0[4 * r + 3] = qa[r].w;
    q1[4 * r] = qb4[r].x; q1[4 * r + 1] = qb4[r].y;
    q1[4 * r + 2] = qb4[r].z; q1[4 * r + 3] = qb4[r].w;
  }
  __syncthreads();
  float m0 = -INFINITY, l0 = 0.f, m1 = -INFINITY, l1 = 0.f;
  float acc0[16], acc1[16];
#pragma unroll
  for (int d = 0; d < 16; ++d) { acc0[d] = 0.f; acc1[d] = 0.f; }

#pragma unroll
  for (int ch = 0; ch < 4; ++ch) {         // 16-key chunks
    float sc0[16], sc1[16];
#pragma unroll
    for (int j = 0; j < 16; ++j) {
      const float* kp = kl + (ch * 16 + j) * 16;
      float s0 = 0.f, s1 = 0.f;
#pragma unroll
      for (int d = 0; d < 16; ++d) { float kv_ = kp[d]; s0 += q0[d] * kv_; s1 += q1[d] * kv_; }
      sc0[j] = s0 * SCALE; sc1[j] = s1 * SCALE;
    }
    float mb0 = sc0[0], mb1 = sc1[0];
#pragma unroll
    for (int j = 1; j < 16; ++j) { mb0 = fmaxf(mb0, sc0[j]); mb1 = fmaxf(mb1, sc1[j]); }
    float mn0 = fmaxf(m0, mb0), mn1 = fmaxf(m1, mb1);
    float r0 = exp2f((m0 - mn0) * LOG2E), r1 = exp2f((m1 - mn1) * LOG2E);
    l0 *= r0; l1 *= r1;
#pragma unroll
    for (int d = 0; d < 16; ++d) { acc0[d] *= r0; acc1[d] *= r1; }
#pragma unroll
    for (int j = 0; j < 16; ++j) {
      float w0 = exp2f((sc0[j] - mn0) * LOG2E), w1 = exp2f((sc1[j] - mn1) * LOG2E);
      l0 += w0; l1 += w1; sc0[j] = w0; sc1[j] = w1;
    }
#pragma unroll
    for (int j = 0; j < 16; ++j) {
      const float* vp = vl + (ch * 16 + j) * 16;
      float w0 = sc0[j], w1 = sc1[j];
#pragma unroll
      for (int d = 0; d < 16; ++d) { float vv = vp[d]; acc0[d] += w0 * vv; acc1[d] += w1 * vv; }
    }
    m0 = mn0; m1 = mn1;
  }
  const int pbase = (head * NSPLIT + sp) * NTOK;
  pm[pbase + i0] = m0; pm[pbase + i1] = m1;
  pl[pbase + i0] = l0; pl[pbase + i1] = l1;
  float4* pa0 = (float4*)(pacc + (size_t)(pbase + i0) * 16);
  float4* pa1 = (float4*)(pacc + (size_t)(pbase + i1) * 16);
#pragma unroll
  for (int r = 0; r < 4; ++r) {
    float4 v0; v0.x = acc0[4 * r]; v0.y = acc0[4 * r + 1]; v0.z = acc0[4 * r + 2]; v0.w = acc0[4 * r + 3];
    pa0[r] = v0;
    float4 v1; v1.x = acc1[4 * r]; v1.y = acc1[4 * r + 1]; v1.z = acc1[4 * r + 2]; v1.w = acc1[4 * r + 3];
    pa1[r] = v1;
  }
}

__global__ __launch_bounds__(256) void attp_kernel(int t, float* __restrict__ ws) {
  __shared__ float smem[2048];
  attp_body(blockIdx.x, threadIdx.x, t, ws + OFF_KV, ws + OFF_Q,
            ws + OFF_PM, ws + OFF_PL, ws + OFF_PACC, smem);
}

// ---------------------------------------------------------------------------
// combine partials -> att ; su = h@A.T + att@Wo.T + bo ; LIF-S; q(t+1).
// One wave per token. Sparse A/Wq terms (~1.3 set bits/lane) read DIRECT
// from global (L2-resident 16KB each); only Wo (dense use) staged in LDS.
// Ascending-k sparse sums == dense fma chain exactly.
// ---------------------------------------------------------------------------
__global__ __launch_bounds__(256) void combine_lifs_kernel(
    int t, const float* __restrict__ A, const float* __restrict__ Wq,
    const float* __restrict__ bq, const float* __restrict__ Wo,
    const float* __restrict__ bo, const float* __restrict__ thr_s0,
    float* __restrict__ ws) {
  __shared__ float Wos[64 * 68];           // row-major, c x k
  __shared__ float att_s[4][64];
  __shared__ int scnt;
  const int tid = threadIdx.x;
#pragma unroll
  for (int p = 0; p < 4; ++p) {
    int e = tid + p * 256;
    int c = e >> 4, kq = e & 15;
    *(float4*)(Wos + c * 68 + kq * 4) = *(const float4*)(Wo + c * 64 + kq * 4);
  }
  if (tid == 0) scnt = 0;

  const float* pm = ws + OFF_PM;
  const float* pl = ws + OFF_PL;
  const float* pacc = ws + OFF_PACC;
  float* sv = ws + OFF_SV;
  float* qb = ws + OFF_Q;
  int* cnt = (int*)(ws + OFF_CNT);
  unsigned long long* hmask = (unsigned long long*)(ws + OFF_HM);

  const int lane = tid & 63, w = tid >> 6;
  const int n = blockIdx.x * 4 + w;
  const int head = lane >> 4, d = lane & 15;
  const int pb = head * NSPLIT * NTOK + n;

  float mstar = -INFINITY;
  for (int s = 0; s < NSPLIT; ++s) mstar = fmaxf(mstar, pm[pb + s * NTOK]);
  float lst = 0.f, av = 0.f;
  for (int s = 0; s < NSPLIT; ++s) {
    float e = exp2f((pm[pb + s * NTOK] - mstar) * LOG2E);
    lst += e * pl[pb + s * NTOK];
    av += e * pacc[(size_t)(pb + s * NTOK) * 16 + d];
  }
  att_s[w][lane] = av / lst;               // same-wave LDS row
  unsigned long long hm = hmask[n];        // previous spike mask, wave-uniform

  // sparse st = sum_{k in hm} A[lane][k]  (direct L2; ascending k)
  float st = 0.f;
  {
    unsigned long long m = hm;
    while (m) {
      int k = __builtin_ctzll(m);
      m &= m - 1;
      st += A[lane * 64 + k];
    }
  }
  __syncthreads();                          // Wos staged

  // dense wo = sum_k att[k]*Wo[lane][k]
  const float* Wor = Wos + lane * 68;
  float wo = 0.f;
#pragma unroll
  for (int kq = 0; kq < 16; ++kq) {
    float4 wb = *(const float4*)(Wor + kq * 4);
    float4 ab = *(const float4*)(&att_s[w][kq * 4]);
    wo += ab.x * wb.x; wo += ab.y * wb.y; wo += ab.z * wb.z; wo += ab.w * wb.w;
  }
  float su = st + wo + bo[lane];

  float thr = thr_s0[0];
  const float inv = 1.0f / 131072.0f;      // 2048*64 (power of 2 -> exact)
  for (int i = 0; i < t; ++i) {
    float mean = (float)cnt[i] * inv;
    thr = fmaxf(thr + 0.1f * (mean - 0.02f), 0.5f);
  }
  float svo = sv[n * 64 + lane];
  float vpot = svo * MEMDECAY + su;
  float spk = (vpot >= thr) ? 1.f : 0.f;
  sv[n * 64 + lane] = vpot * (1.f - spk);
  unsigned long long sm = __ballot(spk > 0.5f);  // wave-uniform

  // sparse q = sum_{k in sm} Wq[lane][k] + bq[lane]  (direct L2)
  float qv = 0.f;
  {
    unsigned long long m = sm;
    while (m) {
      int k = __builtin_ctzll(m);
      m &= m - 1;
      qv += Wq[lane * 64 + k];
    }
  }
  qb[n * 64 + lane] = qv + bq[lane];

  if (lane == 0) {
    hmask[n] = sm;
    atomicAdd(&scnt, __popcll(sm));
  }
  __syncthreads();
  if (tid == 0) atomicAdd(&cnt[t], scnt);
}

// ---------------------------------------------------------------------------
// LIF-O sparse: out_pot[n][c] = sum_{k in hmask[n]} C_t[k][c]; fused LIF
// epilogue. C_t L2-resident, no staging. Fused with attp(t+1) in [256,768).
// ---------------------------------------------------------------------------
__global__ __launch_bounds__(256) void fused_out_attp_kernel(
    int t, const float* __restrict__ thr_o0, float* __restrict__ out,
    float* __restrict__ ws) {
  __shared__ float smem[2048];              // attp kl|vl only
  __shared__ int scnt;
  const int blk = blockIdx.x;
  if (blk >= 256) {
    attp_body(blk - 256, threadIdx.x, t + 1, ws + OFF_KV, ws + OFF_Q,
              ws + OFF_PM, ws + OFF_PL, ws + OFF_PACC, smem);
    return;
  }
  const int tid = threadIdx.x;
  const int nt = blk >> 3;                  // token tile 0..31
  const int ct = blk & 7;                   // channel tile 0..7
  const float* Ct = ws + OFF_CT;
  float* ov = ws + OFF_OV;
  int* cnt = (int*)(ws + OFF_CNT);
  const unsigned long long* hmask = (const unsigned long long*)(ws + OFF_HM);

  if (tid == 0) scnt = 0;
  __syncthreads();

  const int tr = tid >> 4, tc = tid & 15;   // rows tr+i*16, cols tc*4+j
  float thr = thr_o0[0];
  const float inv = 1.0f / 1048576.0f;      // 2048*512
  for (int i = 0; i < t; ++i) {
    float mean = (float)cnt[16 + i] * inv;
    thr = fmaxf(thr + 0.1f * (mean - 0.02f), 0.5f);
  }

  int mycount = 0;
#pragma unroll
  for (int i = 0; i < 4; ++i) {
    int n = nt * 64 + tr + i * 16;
    size_t coff = (size_t)ct * 64 + tc * 4;
    // sparse gather: ascending-k adds == dense fma chain (h in {0,1})
    float a0 = 0.f, a1 = 0.f, a2 = 0.f, a3 = 0.f;
    unsigned long long m = hmask[n];
    while (m) {
      int k = __builtin_ctzll(m);
      m &= m - 1;
      float4 c = *(const float4*)(Ct + (size_t)k * 512 + coff);
      a0 += c.x; a1 += c.y; a2 += c.z; a3 += c.w;
    }
    int b = n >> 8, s = n & 255;
    float* ovp = ov + (size_t)n * 512 + coff;
    float* outp = out + ((size_t)(b * 16 + t) * 256 + s) * 512 + coff;
    float4 o = *(float4*)ovp;
    float v0 = o.x * MEMDECAY + a0;
    float v1 = o.y * MEMDECAY + a1;
    float v2 = o.z * MEMDECAY + a2;
    float v3 = o.w * MEMDECAY + a3;
    float s0 = (v0 >= thr) ? 1.f : 0.f;
    float s1 = (v1 >= thr) ? 1.f : 0.f;
    float s2 = (v2 >= thr) ? 1.f : 0.f;
    float s3 = (v3 >= thr) ? 1.f : 0.f;
    float4 sp; sp.x = s0; sp.y = s1; sp.z = s2; sp.w = s3;
    *(float4*)outp = sp;
    float4 nv; nv.x = v0 * (1.f - s0); nv.y = v1 * (1.f - s1);
    nv.z = v2 * (1.f - s2); nv.w = v3 * (1.f - s3);
    *(float4*)ovp = nv;
    mycount += (int)(s0 + s1 + s2 + s3);
  }
  atomicAdd(&scnt, mycount);
  __syncthreads();
  if (tid == 0) atomicAdd(&cnt[16 + t], scnt);
}

// ---------------------------------------------------------------------------
extern "C" void kernel_launch(void* const* d_in, const int* in_sizes, int n_in,
                              void* d_out, int out_size, void* d_ws, size_t ws_size,
                              hipStream_t stream) {
  const float* x    = (const float*)d_in[0];
  const float* A    = (const float*)d_in[1];
  const float* C    = (const float*)d_in[2];
  const float* Wq   = (const float*)d_in[3];
  const float* bq   = (const float*)d_in[4];
  const float* Wkv  = (const float*)d_in[5];
  const float* bkv  = (const float*)d_in[6];
  const float* Wo   = (const float*)d_in[7];
  const float* bo   = (const float*)d_in[8];
  const float* th_s = (const float*)d_in[9];
  const float* th_o = (const float*)d_in[10];
  float* out = (float*)d_out;
  float* ws = (float*)d_ws;

  init_kernel<<<dim3(2181), dim3(256), 0, stream>>>(bq, C, Wkv, ws);
  kv_gemm_kernel<<<dim3(512), dim3(256), 0, stream>>>(x, ws + OFF_WT, bkv, ws);
  attp_kernel<<<dim3(512), dim3(256), 0, stream>>>(0, ws);
  for (int t = 0; t < TSTEPS; ++t) {
    combine_lifs_kernel<<<dim3(512), dim3(256), 0, stream>>>(t, A, Wq, bq, Wo, bo, th_s, ws);
    int g = (t < TSTEPS - 1) ? 768 : 256;
    fused_out_attp_kernel<<<dim3(g), dim3(256), 0, stream>>>(t, th_o, out, ws);
  }
}